// Round 10
// baseline (3501.078 us; speedup 1.0000x reference)
//
#include <hip/hip_runtime.h>
#include <math.h>

#define Bb 4
#define Ls 2048
#define Dd 1024
#define Hh 16
#define HDm 64
#define ML (Bb*Ls)   /* 8192 rows */

typedef double f64x4 __attribute__((ext_vector_type(4)));
typedef float  f32x4 __attribute__((ext_vector_type(4)));
typedef short  bf16x8 __attribute__((ext_vector_type(8)));
typedef unsigned int u32;
typedef unsigned short u16;

// HBM -> LDS direct (no VGPR round-trip). LDS dest = wave-uniform base +
// lane*16 (m104); global src is per-lane. size must be literal 16 (m97).
__device__ __forceinline__ void gload16(const void* g, void* l) {
  __builtin_amdgcn_global_load_lds(
      (const __attribute__((address_space(1))) u32*)g,
      (__attribute__((address_space(3))) u32*)l, 16, 0, 0);
}

// f32 -> bf16, round-to-nearest-even (finite inputs only)
__device__ __forceinline__ u16 f2bf(float f) {
  u32 u = __float_as_uint(f);
  u += 0x7FFFu + ((u >> 16) & 1u);
  return (u16)(u >> 16);
}

// ---------------------------------------------------------------------------
// f32 -> bf16 elementwise (operand pre-conversion for bf16 GEMMs).
// ---------------------------------------------------------------------------
__global__ __launch_bounds__(256) void f32_to_bf16(
    const float* __restrict__ in, u16* __restrict__ out, int n8) {
  int i = blockIdx.x * 256 + threadIdx.x;
  if (i >= n8) return;
  const float4* p = (const float4*)(in + (size_t)i * 8);
  float4 a = p[0], c = p[1];
  union { u16 h[8]; uint4 v; } o;
  o.h[0] = f2bf(a.x); o.h[1] = f2bf(a.y); o.h[2] = f2bf(a.z); o.h[3] = f2bf(a.w);
  o.h[4] = f2bf(c.x); o.h[5] = f2bf(c.y); o.h[6] = f2bf(c.z); o.h[7] = f2bf(c.w);
  *(uint4*)(out + (size_t)i * 8) = o.v;
}

// ---------------------------------------------------------------------------
// Limb extraction: x -> v = rint(x*scale) (<=32 bits) -> 5 balanced 7-bit
// limbs li in [-64,63], v = sum li*2^(7i). Each limb stored as bf16 (exact).
// Planes: dst[p*planeStride + i].
// ---------------------------------------------------------------------------
__global__ __launch_bounds__(256) void extract_limbs(
    const float* __restrict__ src, u16* __restrict__ dst,
    size_t planeStride, double scale, int n) {
  int i = blockIdx.x * 256 + threadIdx.x;
  if (i >= n) return;
  long long v = (long long)rint((double)src[i] * scale);
#pragma unroll
  for (int p = 0; p < 5; p++) {
    int li = (int)(((v + 64) & 127) - 64);
    v = (v - li) >> 7;
    dst[planeStride * p + i] = f2bf((float)li);
  }
}

// ---------------------------------------------------------------------------
// Fixed-point NT GEMM on the bf16 matrix pipe, EXACT integer arithmetic:
// C[m,n] = oscale' * sum_k A[m,k]*W[n,k] with A,W pre-limbized (5 balanced
// 7-bit limbs each; A scale 2^28, W scale 2^23).
//   - limb values |l|<=64 exact in bf16; limb-pair products <=2^12; 1024-term
//     dots <=2^22 -> EXACT in the f32 MFMA accumulator.
//   - pairs (i,j) with s=i+j>=2 (22 of 25; s<=1 contributes <2^-20) chained
//     into 7 s-bucket accs (bucket sums ~2^18 rms, exact).
//   - combine: C = (sum_b acc_b*128^b) * outscale * 2^-37  (f64 Horner).
// Total error = input rounding only: sigma_logit ~ 0.0024 << min gap ~2.
// Replaces the f64-MFMA projections (round-8 finding: f64 pipe ceiling
// ~30.7 TF -> 550us each; this runs on the 2075 TF bf16 pipe).
// C tile 32x64, 4 waves 2x2 (wave tile 16x32); K-step 32, double-buffered
// gload16 staging (30 x 1KB wave-chunks); rule-21 both-sides XOR swizzle
// g = s ^ ((row>>1)&3) -> conflict-free b128 frag reads.
// Frag layouts (validated: attn PV + gemm_nt_bf16): A row=lane&15,
// k=8*(lane>>4)+j; B col=lane&15 same k; D col=lane&15, row=4*(lane>>4)+reg.
// LDS: 2 x (A 5x2048 + B 5x4096) = 61440 B.
// ---------------------------------------------------------------------------
__global__ __launch_bounds__(256) void gemm_nt_limb(
    const u16* __restrict__ AL, const u16* __restrict__ WL,
    double* __restrict__ C, int aPlaneElems, double oscale) {
  __shared__ __align__(16) u16 lbuf[2][15360];   // 30720 B per buffer
  const int tid = threadIdx.x;
  const int lane = tid & 63;
  const int w = tid >> 6;
  const int wr = w >> 1, wc = w & 1;
  const int lrow = lane & 15, lk = lane >> 4;
  const int slk = lk ^ ((lrow >> 1) & 3);        // read-side swizzle slot
  const int bm = blockIdx.y * 32, bn = blockIdx.x * 64;

  // staging: 30 chunks of 1KB (A: 0..9 = 5 planes x 32rows x 64B;
  // B: 10..29 = 5 planes x 64rows x 64B); wave w takes c = w, w+4, ...
  const u16* gp[8];
#pragma unroll
  for (int t = 0; t < 8; t++) {
    int c = w + 4 * t;
    if (c < 30) {
      if (c < 10) {
        int p = c >> 1;
        int row = ((c & 1) << 4) + (lane >> 2);
        int g = (lane & 3) ^ ((row >> 1) & 3);   // write-side swizzle
        gp[t] = AL + (size_t)p * aPlaneElems + (size_t)(bm + row) * 1024 + g * 8;
      } else {
        int cb = c - 10;
        int p = cb >> 2;
        int row = ((cb & 3) << 4) + (lane >> 2);
        int g = (lane & 3) ^ ((row >> 1) & 3);
        gp[t] = WL + (size_t)p * (1024 * 1024) + (size_t)(bn + row) * 1024 + g * 8;
      }
    }
  }

  f32x4 acc[7][2];
#pragma unroll
  for (int b = 0; b < 7; b++)
#pragma unroll
    for (int q = 0; q < 2; q++) acc[b][q] = (f32x4){0.f, 0.f, 0.f, 0.f};

#pragma unroll
  for (int t = 0; t < 8; t++) {       // stage k-step 0 into buffer 0
    int c = w + 4 * t;
    if (c < 30) gload16(gp[t], (char*)&lbuf[0][0] + c * 1024);
  }
  __syncthreads();

  const int abyte = (16 * wr + lrow) * 64 + slk * 16;
  const int bbyte0 = 10240 + (32 * wc + lrow) * 64 + slk * 16;
  const int bbyte1 = 10240 + (32 * wc + 16 + lrow) * 64 + slk * 16;

  int cur = 0;
  for (int step = 0; step < 32; step++) {
    if (step < 31) {                  // prefetch next k-tile into buf^1
#pragma unroll
      for (int t = 0; t < 8; t++) {
        int c = w + 4 * t;
        if (c < 30) {
          gp[t] += 32;
          gload16(gp[t], (char*)&lbuf[cur ^ 1][0] + c * 1024);
        }
      }
    }
    const char* bb = (const char*)&lbuf[cur][0];
    bf16x8 af[5];
#pragma unroll
    for (int i = 0; i < 5; i++)
      af[i] = *(const bf16x8*)(bb + i * 2048 + abyte);
#pragma unroll
    for (int j = 0; j < 5; j++) {
      bf16x8 b0 = *(const bf16x8*)(bb + j * 4096 + bbyte0);
      bf16x8 b1 = *(const bf16x8*)(bb + j * 4096 + bbyte1);
#pragma unroll
      for (int i = 0; i < 5; i++) {
        if (i + j >= 2) {
          acc[i + j - 2][0] = __builtin_amdgcn_mfma_f32_16x16x32_bf16(
              af[i], b0, acc[i + j - 2][0], 0, 0, 0);
          acc[i + j - 2][1] = __builtin_amdgcn_mfma_f32_16x16x32_bf16(
              af[i], b1, acc[i + j - 2][1], 0, 0, 0);
        }
      }
    }
    __syncthreads();   // drains vmcnt (prefetch landed) + releases buf[cur]
    cur ^= 1;
  }

  // combine: C = (sum_b acc_b * 128^b) * oscale   (oscale = outscale*2^-37)
#pragma unroll
  for (int q = 0; q < 2; q++)
#pragma unroll
    for (int r = 0; r < 4; r++) {
      double t = (double)acc[6][q][r];
#pragma unroll
      for (int b = 5; b >= 0; b--) t = t * 128.0 + (double)acc[b][q][r];
      size_t m = (size_t)(bm + 16 * wr + 4 * lk + r);
      C[m * 1024 + bn + 32 * wc + 16 * q + lrow] = t * oscale;
    }
}

// ---------------------------------------------------------------------------
// NT GEMM on the bf16 matrix pipe (round-9 version, passed): C = A @ B^T,
// f32 accumulate; output bf16 (Cb) or f32+bias (Cf). V projection & out0.
// ---------------------------------------------------------------------------
__global__ __launch_bounds__(256) void gemm_nt_bf16(
    const u16* __restrict__ A, const u16* __restrict__ B,
    const float* __restrict__ bias, u16* __restrict__ Cb,
    float* __restrict__ Cf) {
  const int K = Dd;
  __shared__ __align__(16) u16 Asb[2][64 * 32];
  __shared__ __align__(16) u16 Bsb[2][64 * 32];
  const int tid = threadIdx.x;
  const int lane = tid & 63;
  const int w = tid >> 6;
  const int lrow = lane & 15, lk = lane >> 4;
  const int bm = blockIdx.y * 64, bn = blockIdx.x * 64;

  const int srow = 16 * w + (lane >> 2);
  const u16* ga = A + (size_t)(bm + srow) * K + 8 * (lane & 3);
  const u16* gb = B + (size_t)(bn + srow) * K + 8 * (lane & 3);
  char* la0 = (char*)&Asb[0][0] + w * 1024;
  char* lb0 = (char*)&Bsb[0][0] + w * 1024;
  char* la1 = (char*)&Asb[1][0] + w * 1024;
  char* lb1 = (char*)&Bsb[1][0] + w * 1024;

  f32x4 acc[4] = {{0.f,0.f,0.f,0.f},{0.f,0.f,0.f,0.f},
                  {0.f,0.f,0.f,0.f},{0.f,0.f,0.f,0.f}};

  gload16(ga, la0);
  gload16(gb, lb0);
  __syncthreads();

  int cur = 0;
  for (int k0 = 32; k0 <= K; k0 += 32) {
    if (k0 < K) {
      gload16(ga + k0, cur ? la0 : la1);
      gload16(gb + k0, cur ? lb0 : lb1);
    }
    const u16* Ab = &Asb[cur][0];
    const u16* Bt = &Bsb[cur][0];
    bf16x8 afr = *(const bf16x8*)&Ab[(16 * w + lrow) * 32 + 8 * lk];
#pragma unroll
    for (int j = 0; j < 4; j++) {
      bf16x8 bfr = *(const bf16x8*)&Bt[(16 * j + lrow) * 32 + 8 * lk];
      acc[j] = __builtin_amdgcn_mfma_f32_16x16x32_bf16(afr, bfr, acc[j], 0, 0, 0);
    }
    __syncthreads();
    cur ^= 1;
  }

#pragma unroll
  for (int j = 0; j < 4; j++)
#pragma unroll
    for (int r = 0; r < 4; r++) {
      size_t m = (size_t)(bm + 16 * w + 4 * lk + r);
      int n = bn + 16 * j + lrow;
      float v = acc[j][r];
      if (bias) v += bias[n];
      if (Cf) Cf[m * Dd + n] = v;
      else    Cb[m * Dd + n] = f2bf(v);
    }
}

// ---------------------------------------------------------------------------
// One-sweep flash attention, v8b (UNCHANGED from round 9 pass, 1377us):
// PV on bf16 matrix pipe; K/V double-buffered global_load_lds; Q in regs;
// softmax f64-MFMA-D-layout rows 4d+lk; Fs crosses f64-D <-> bf16-D layouts;
// O written bf16. LDS 45312 B -> 3 blocks/CU.
// ---------------------------------------------------------------------------
__global__ __launch_bounds__(256) void attn_flash(
    double* __restrict__ Qd, const double* __restrict__ Kd,
    const u16* __restrict__ Vf, float* __restrict__ attn,
    u16* __restrict__ O) {
  __shared__ __align__(16) double Kbuf[2][32 * 64];
  __shared__ __align__(16) u16    Vb16[2][32 * 64];  // [key][dim] bf16
  __shared__ __align__(16) u16    Pb[4][16 * 32];    // per-wave [row][key] bf16
  __shared__ __align__(16) float  Fs[4][16];         // per-wave per-row scalar

  const int tid = threadIdx.x;
  const int lane = tid & 63;
  const int w = tid >> 6;             // wave 0..3 -> q-row strip 16w
  const int lrow = lane & 15;         // A-row / B,D-col index
  const int lk = lane >> 4;           // k-group index / D row bits
  const int blk = blockIdx.x;
  const int qt = blk & 31;            // 32 q-tiles of 64 rows
  const int h = (blk >> 5) & 15;      // head
  const int b = blk >> 9;
  const int l0 = qt * 64;

  const double* Qg = Qd + ((size_t)(b * Ls + l0)) * Dd + h * HDm;
  const double* Kg = Kd + ((size_t)b * Ls) * Dd + h * HDm;
  const u16*    Vg = Vf + ((size_t)b * Ls) * Dd + h * HDm;
  float* aout = attn + ((size_t)((b * Hh + h) * Ls + l0)) * Ls;

  // Q fragments: lane holds Q[16w+lrow][4t+lk] for t=0..15 (whole sweep);
  // Qd is pre-scaled by 0.125 at projection time.
  double qreg[16];
#pragma unroll
  for (int t = 0; t < 16; t++)
    qreg[t] = Qg[(size_t)(16 * w + lrow) * Dd + 4 * t + lk];

  // K staging geometry (v7, validated): linear [32][64] f64 with XOR swizzle
  // byte^=(row&7)<<4 on BOTH sides (pre-swizzled global src + XOR'd read).
  const int l16 = (lane & 31) * 16;
  const int halfk = lane >> 5;
  const int sx = (lrow & 7) << 1;     // K read swizzle (element units)

  auto stage = [&](int kts, int bsel) {
#pragma unroll
    for (int jj = 0; jj < 4; jj++) {
      int i = w + 4 * jj;
      int row = 2 * i + halfk;
      int inner = l16 ^ ((row & 7) << 4);   // pre-swizzled global source
      const char* g = (const char*)Kg + (((size_t)(kts * 32 + row)) << 13) + inner;
      gload16(g, (char*)(&Kbuf[bsel][0]) + i * 1024);
    }
    // V: wave w stages keys 8w..8w+7 bf16 (1KB)
    {
      const char* g = (const char*)Vg +
          ((size_t)(kts * 32 + 8 * w + (lane >> 3))) * (Dd * 2) + (lane & 7) * 16;
      gload16(g, (char*)(&Vb16[bsel][0]) + w * 1024);
    }
  };

  float mreff[4];
  double sacc[4];
  f32x4 pacc[4];   // PV accum per dim-quadrant; D: col=lrow, row=4*lk+reg
#pragma unroll
  for (int d = 0; d < 4; d++) {
    mreff[d] = -INFINITY;
    sacc[d] = 0.0;
    pacc[d] = (f32x4){0.f, 0.f, 0.f, 0.f};
  }

  stage(0, 0);
  __syncthreads();   // drains vmcnt(0): tile 0 resident for all waves

  int cur = 0;
  for (int kt = 0; kt < 64; kt++) {
    if (kt < 63) stage(kt + 1, cur ^ 1);   // async: lands during compute

    const double* Kb = &Kbuf[cur][0];

    // QK^T: E[r][c] = sum_k Q[r][k] K[c][k]; quadrant 0: keys 0-15, 1: 16-31
    f64x4 acc0 = {0.0, 0.0, 0.0, 0.0};
    f64x4 acc1 = {0.0, 0.0, 0.0, 0.0};
#pragma unroll
    for (int t = 0; t < 16; t++) {
      int ko = (4 * t + lk) ^ sx;
      double b0 = Kb[lrow * 64 + ko];
      double b1 = Kb[(16 + lrow) * 64 + ko];
      acc0 = __builtin_amdgcn_mfma_f64_16x16x4f64(qreg[t], b0, acc0, 0, 0, 0);
      acc1 = __builtin_amdgcn_mfma_f64_16x16x4f64(qreg[t], b1, acc1, 0, 0, 0);
    }

    // online softmax per owned row: acc[d] is row 4*d + lk (f64 D layout),
    // col lrow (acc0) / 16+lrow (acc1). Logits pre-scaled via Q.
#pragma unroll
    for (int d = 0; d < 4; d++) {
      double e0 = acc0[d];
      double e1 = acc1[d];
      float tmf = fmaxf((float)e0, (float)e1);
#pragma unroll
      for (int m = 1; m < 16; m <<= 1) tmf = fmaxf(tmf, __shfl_xor(tmf, m));
      float mo_f = mreff[d];
      float ref_f = fmaxf(mo_f, tmf);        // float-rounded running ref
      double ref = (double)ref_f;
      float p0 = expf((float)(e0 - ref));
      float p1 = expf((float)(e1 - ref));
      double ts = (double)p0 + (double)p1;
#pragma unroll
      for (int m = 1; m < 16; m <<= 1) ts += __shfl_xor(ts, m);
      float factor = expf(mo_f - ref_f);     // <= 1
      sacc[d] = sacc[d] * (double)factor + ts;
      mreff[d] = ref_f;
      int row = 16 * w + 4 * d + lk;
      aout[(size_t)row * Ls + kt * 32 + lrow] = p0;
      aout[(size_t)row * Ls + kt * 32 + 16 + lrow] = p1;
      if (lrow == 0) {  // stash per-(row,tile) ref; publish rescale factor
        ((float*)(Qd + ((size_t)(b * Ls + l0 + row)) * Dd + h * HDm))[kt] = ref_f;
        Fs[w][4 * d + lk] = factor;
      }
      // P tile in A-operand layout: Pb[row 4d+lk][key] bf16
      Pb[w][(4 * d + lk) * 32 + lrow] = f2bf(p0);
      Pb[w][(4 * d + lk) * 32 + 16 + lrow] = f2bf(p1);
    }

    // PV on matrix pipe (wave-internal LDS order: reads see writes above).
    bf16x8 afr = *(const bf16x8*)&Pb[w][lrow * 32 + 8 * lk];
    f32x4 fv = *(const f32x4*)&Fs[w][4 * lk];   // factors for rows 4lk+0..3
    const u16* Vb = &Vb16[cur][0];
#pragma unroll
    for (int q = 0; q < 4; q++) {
      pacc[q][0] *= fv[0];
      pacc[q][1] *= fv[1];
      pacc[q][2] *= fv[2];
      pacc[q][3] *= fv[3];
      bf16x8 bfr;  // B frag: V[k=8*lk+r][col=16q+lrow]
#pragma unroll
      for (int r = 0; r < 8; r++)
        bfr[r] = (short)Vb[(8 * lk + r) * 64 + 16 * q + lrow];
      pacc[q] = __builtin_amdgcn_mfma_f32_16x16x32_bf16(afr, bfr, pacc[q], 0, 0, 0);
    }

    __syncthreads();  // drains vmcnt (prefetch landed) + publishes buf^1
    cur ^= 1;
  }

  // epilogue: publish 1/s per row (rows 4d+lk), read per PV layout (4lk+r)
  if (lrow == 0) {
#pragma unroll
    for (int d = 0; d < 4; d++) Fs[w][4 * d + lk] = (float)(1.0 / sacc[d]);
  }
  f32x4 sv = *(const f32x4*)&Fs[w][4 * lk];
#pragma unroll
  for (int q = 0; q < 4; q++)
#pragma unroll
    for (int r = 0; r < 4; r++) {
      int row = 16 * w + 4 * lk + r;
      O[((size_t)(b * Ls + l0 + row)) * Dd + h * HDm + 16 * q + lrow] =
          f2bf(pacc[q][r] * sv[r]);
    }
  if (lrow == 0) {
#pragma unroll
    for (int d = 0; d < 4; d++) {
      int row = 16 * w + 4 * d + lk;
      float* mrow = (float*)(Qd + ((size_t)(b * Ls + l0 + row)) * Dd + h * HDm);
      mrow[64] = mreff[d];
      *(double*)(mrow + 66) = sacc[d];
    }
  }
}

// ---------------------------------------------------------------------------
// Rescale: p = p~ * exp(ref_t - ref_final) / s. One block per attention row.
// ---------------------------------------------------------------------------
__global__ __launch_bounds__(256) void attn_scale(
    float* __restrict__ attn, const double* __restrict__ Qd) {
  int R = blockIdx.x;                 // 0..131071: ((b*Hh+h)*Ls + l)
  int b = R >> 15;
  int rem = R & 32767;
  int h = rem >> 11;
  int l = rem & 2047;
  const float* mrow = (const float*)(Qd + ((size_t)(b * Ls + l)) * Dd + h * HDm);
  int tid = threadIdx.x;
  int kt = tid >> 2;                  // 8 cols per thread, within one 32-col tile
  double mt = (double)mrow[kt];
  double mf = (double)mrow[64];
  double s = *(const double*)(mrow + 66);
  float sc = (float)(exp(mt - mf) / s);
  float4* ap = (float4*)(attn + (size_t)R * Ls + tid * 8);
  float4 a0 = ap[0], a1 = ap[1];
  a0.x *= sc; a0.y *= sc; a0.z *= sc; a0.w *= sc;
  a1.x *= sc; a1.y *= sc; a1.z *= sc; a1.w *= sc;
  ap[0] = a0; ap[1] = a1;
}

// ---------------------------------------------------------------------------
extern "C" void kernel_launch(void* const* d_in, const int* in_sizes, int n_in,
                              void* d_out, int out_size, void* d_ws, size_t ws_size,
                              hipStream_t stream) {
  const float* query = (const float*)d_in[0];
  const float* key   = (const float*)d_in[1];
  const float* value = (const float*)d_in[2];
  const float* Wq    = (const float*)d_in[3];
  const float* Wk    = (const float*)d_in[4];
  const float* Wv    = (const float*)d_in[5];
  const float* Wo    = (const float*)d_in[6];
  const float* bo    = (const float*)d_in[7];

  float* out0 = (float*)d_out;            // [B,L,D]
  float* attn = out0 + (size_t)ML * Dd;   // [B,H,L,L]

  // ws layout (bytes):
  // Qd 64M | Kd 64M | Vfb 16M | Ofb 16M | valb 16M | Wvb 2M | Wob 2M |
  // LW 10M (5 planes Dd^2 bf16) | LA 40M (5 planes x 4096x1024 bf16, reused)
  char* ws = (char*)d_ws;
  double* Qd   = (double*)ws;
  double* Kd   = (double*)(ws + 67108864ull);
  u16*    Vfb  = (u16*)(ws + 134217728ull);
  u16*    Ofb  = (u16*)(ws + 150994944ull);
  u16*    valb = (u16*)(ws + 167772160ull);
  u16*    Wvb  = (u16*)(ws + 184549376ull);
  u16*    Wob  = (u16*)(ws + 186646528ull);
  u16*    LW   = (u16*)(ws + 188743680ull);
  u16*    LA   = (u16*)(ws + 199229440ull);

  const int halfElems = (ML / 2) * Dd;            // 4194304
  const int wElems = Dd * Dd;                     // 1048576
  const double SA = 268435456.0;                  // 2^28 (query/key)
  const double SW = 8388608.0;                    // 2^23 (weights)
  const double OSQ = 0.125 / 137438953472.0;      // 0.125 * 2^-37
  const double OSK = 1.0 / 137438953472.0;        // 1.0   * 2^-37

  dim3 gemm_grid(Dd / 64, ML / 64);
  dim3 limb_grid(Dd / 64, (ML / 2) / 32);         // 16 x 128

  // V path (bf16 pipe, round-9 validated)
  f32_to_bf16<<<(ML * Dd / 8) / 256, 256, 0, stream>>>(value, valb, ML * Dd / 8);
  f32_to_bf16<<<(Dd * Dd / 8) / 256, 256, 0, stream>>>(Wv, Wvb, Dd * Dd / 8);
  f32_to_bf16<<<(Dd * Dd / 8) / 256, 256, 0, stream>>>(Wo, Wob, Dd * Dd / 8);
  gemm_nt_bf16<<<gemm_grid, 256, 0, stream>>>(valb, Wvb, nullptr, Vfb, nullptr);

  // Q projection: exact fixed-point on bf16 pipe (Q pre-scaled by 0.125)
  extract_limbs<<<wElems / 256, 256, 0, stream>>>(Wq, LW, (size_t)wElems, SW, wElems);
  extract_limbs<<<halfElems / 256, 256, 0, stream>>>(query, LA, (size_t)halfElems, SA, halfElems);
  gemm_nt_limb<<<limb_grid, 256, 0, stream>>>(LA, LW, Qd, halfElems, OSQ);
  extract_limbs<<<halfElems / 256, 256, 0, stream>>>(query + (size_t)halfElems, LA, (size_t)halfElems, SA, halfElems);
  gemm_nt_limb<<<limb_grid, 256, 0, stream>>>(LA, LW, Qd + (size_t)halfElems, halfElems, OSQ);

  // K projection
  extract_limbs<<<wElems / 256, 256, 0, stream>>>(Wk, LW, (size_t)wElems, SW, wElems);
  extract_limbs<<<halfElems / 256, 256, 0, stream>>>(key, LA, (size_t)halfElems, SA, halfElems);
  gemm_nt_limb<<<limb_grid, 256, 0, stream>>>(LA, LW, Kd, halfElems, OSK);
  extract_limbs<<<halfElems / 256, 256, 0, stream>>>(key + (size_t)halfElems, LA, (size_t)halfElems, SA, halfElems);
  gemm_nt_limb<<<limb_grid, 256, 0, stream>>>(LA, LW, Kd + (size_t)halfElems, halfElems, OSK);

  attn_flash<<<Bb * Hh * (Ls / 64), 256, 0, stream>>>(Qd, Kd, Vfb, attn, Ofb);
  attn_scale<<<Bb * Hh * Ls, 256, 0, stream>>>(attn, Qd);

  // out0 = Of @ Wo^T + bo on bf16 matrix pipe, f32 out
  gemm_nt_bf16<<<gemm_grid, 256, 0, stream>>>(Ofb, Wob, bo, nullptr, out0);
}